// Round 9
// baseline (290.349 us; speedup 1.0000x reference)
//
#include <hip/hip_runtime.h>
#include <hip/hip_fp16.h>

#define NN 512
#define NBLK 4             // blocks per matrix
#define BROWS 128          // rows per block
#define THREADS 512        // 8 waves
#define NWAVE 8
#define RPW 16             // rows per wave
#define NITER 10

union H2U { uint32_t u; __half2 h; };

__device__ __forceinline__ float wave_reduce_sum(float v) {
    #pragma unroll
    for (int off = 32; off > 0; off >>= 1)
        v += __shfl_xor(v, off, 64);
    return v;   // all 64 lanes hold the sum
}

__device__ __forceinline__ uint4 pack8(const float e[8]) {
    H2U a, b, c, d;
    a.h = __floats2half2_rn(e[0], e[1]);
    b.h = __floats2half2_rn(e[2], e[3]);
    c.h = __floats2half2_rn(e[4], e[5]);
    d.h = __floats2half2_rn(e[6], e[7]);
    return make_uint4(a.u, b.u, c.u, d.u);
}

__device__ __forceinline__ void unpack8(uint4 q, float e[8]) {
    H2U u; float2 f;
    u.u = q.x; f = __half22float2(u.h); e[0] = f.x; e[1] = f.y;
    u.u = q.y; f = __half22float2(u.h); e[2] = f.x; e[3] = f.y;
    u.u = q.z; f = __half22float2(u.h); e[4] = f.x; e[5] = f.y;
    u.u = q.w; f = __half22float2(u.h); e[6] = f.x; e[7] = f.y;
}

template<bool USE_E>
__device__ __forceinline__ void load_row8(const uint32_t* __restrict__ E32,
                                          const float* __restrict__ S,
                                          size_t row_g, int lane, float e[8]) {
    if constexpr (USE_E) {
        uint4 q = *reinterpret_cast<const uint4*>(E32 + row_g * (NN / 2) + lane * 4);
        unpack8(q, e);
    } else {
        const float4* p = reinterpret_cast<const float4*>(S + row_g * NN + lane * 8);
        float4 x0 = p[0], x1 = p[1];
        e[0] = __expf(x0.x); e[1] = __expf(x0.y); e[2] = __expf(x0.z); e[3] = __expf(x0.w);
        e[4] = __expf(x1.x); e[5] = __expf(x1.y); e[6] = __expf(x1.z); e[7] = __expf(x1.w);
    }
}

// Streaming multi-kernel Sinkhorn. R8 lesson: with NBLK=16 the per-block
// B-reduce head re-read as many bytes as the E slice itself (2x traffic).
// NBLK=4 / 512-thr blocks cuts the partial re-read to 6% of E traffic.
// m = bid % nmat: a matrix's 4 blocks differ by multiples of nmat(=128),
// 128%8==0 -> same XCD under round-robin dispatch -> L2-local exchange.
// Iteration barrier = kernel boundary (11 dispatches, graph-replayed).
// Partials parity-double-buffered (read pr / write pw) -> no races, fixed
// summation order everywhere -> deterministic.

template<bool USE_E>
__global__ __launch_bounds__(THREADS)
void k_first(const float* __restrict__ S, uint32_t* __restrict__ E32,
             float* __restrict__ A, float* __restrict__ pw, int nmat) {
    const int m = blockIdx.x % nmat, blk = blockIdx.x / nmat;
    const int lane = threadIdx.x & 63, w = threadIdx.x >> 6;
    __shared__ float part[NWAVE][NN];

    float c[8] = {0.f, 0.f, 0.f, 0.f, 0.f, 0.f, 0.f, 0.f};
    #pragma unroll 4
    for (int r = 0; r < RPW; ++r) {
        const size_t row_g = (size_t)m * NN + blk * BROWS + w * RPW + r;
        const float4* p = reinterpret_cast<const float4*>(S + row_g * NN + lane * 8);
        float4 x0 = p[0], x1 = p[1];
        float e[8];
        e[0] = __expf(x0.x); e[1] = __expf(x0.y); e[2] = __expf(x0.z); e[3] = __expf(x0.w);
        e[4] = __expf(x1.x); e[5] = __expf(x1.y); e[6] = __expf(x1.z); e[7] = __expf(x1.w);
        if constexpr (USE_E)
            *reinterpret_cast<uint4*>(E32 + row_g * (NN / 2) + lane * 4) = pack8(e);
        float rs = wave_reduce_sum(((e[0]+e[1])+(e[2]+e[3]))+((e[4]+e[5])+(e[6]+e[7])));
        const float a = 1.0f / rs;
        if (lane == 0) A[row_g] = a;
        #pragma unroll
        for (int k = 0; k < 8; ++k) c[k] += e[k] * a;
    }
    *reinterpret_cast<float4*>(&part[w][lane * 8])     = make_float4(c[0], c[1], c[2], c[3]);
    *reinterpret_cast<float4*>(&part[w][lane * 8 + 4]) = make_float4(c[4], c[5], c[6], c[7]);
    __syncthreads();
    {
        const int j = threadIdx.x;   // 512 threads cover NN columns
        float s = 0.f;
        #pragma unroll
        for (int k = 0; k < NWAVE; ++k) s += part[k][j];
        pw[((size_t)m * NBLK + blk) * NN + j] = s;
    }
}

template<bool USE_E>
__global__ __launch_bounds__(THREADS)
void k_sweep(const uint32_t* __restrict__ E32, const float* __restrict__ S,
             const float* __restrict__ pr, float* __restrict__ pw,
             float* __restrict__ A, int nmat) {
    const int m = blockIdx.x % nmat, blk = blockIdx.x / nmat;
    const int lane = threadIdx.x & 63, w = threadIdx.x >> 6;
    __shared__ float Bsh[NN];
    __shared__ float part[NWAVE][NN];

    {   // B-phase: complete previous col sums (fixed order, deterministic)
        const int j = threadIdx.x;
        float s = 0.f;
        #pragma unroll
        for (int k = 0; k < NBLK; ++k) s += pr[((size_t)m * NBLK + k) * NN + j];
        Bsh[j] = 1.0f / s;
    }
    __syncthreads();

    float b[8];
    #pragma unroll
    for (int k = 0; k < 8; ++k) b[k] = Bsh[lane * 8 + k];
    float c[8] = {0.f, 0.f, 0.f, 0.f, 0.f, 0.f, 0.f, 0.f};

    #pragma unroll 4
    for (int r = 0; r < RPW; ++r) {
        const size_t row_g = (size_t)m * NN + blk * BROWS + w * RPW + r;
        float e[8];
        load_row8<USE_E>(E32, S, row_g, lane, e);
        float d = ((e[0]*b[0] + e[1]*b[1]) + (e[2]*b[2] + e[3]*b[3])) +
                  ((e[4]*b[4] + e[5]*b[5]) + (e[6]*b[6] + e[7]*b[7]));
        d = wave_reduce_sum(d);
        const float a = 1.0f / d;
        if (lane == 0) A[row_g] = a;
        #pragma unroll
        for (int k = 0; k < 8; ++k) c[k] += e[k] * a;
    }
    *reinterpret_cast<float4*>(&part[w][lane * 8])     = make_float4(c[0], c[1], c[2], c[3]);
    *reinterpret_cast<float4*>(&part[w][lane * 8 + 4]) = make_float4(c[4], c[5], c[6], c[7]);
    __syncthreads();
    {
        const int j = threadIdx.x;
        float s = 0.f;
        #pragma unroll
        for (int k = 0; k < NWAVE; ++k) s += part[k][j];
        pw[((size_t)m * NBLK + blk) * NN + j] = s;
    }
}

template<bool USE_E>
__global__ __launch_bounds__(THREADS)
void k_final(const uint32_t* __restrict__ E32, const float* __restrict__ S,
             const float* __restrict__ pr, const float* __restrict__ A,
             float* __restrict__ out, int nmat) {
    const int m = blockIdx.x % nmat, blk = blockIdx.x / nmat;
    const int lane = threadIdx.x & 63, w = threadIdx.x >> 6;
    __shared__ float Bsh[NN];

    {
        const int j = threadIdx.x;
        float s = 0.f;
        #pragma unroll
        for (int k = 0; k < NBLK; ++k) s += pr[((size_t)m * NBLK + k) * NN + j];
        Bsh[j] = 1.0f / s;
    }
    __syncthreads();

    float b[8];
    #pragma unroll
    for (int k = 0; k < 8; ++k) b[k] = Bsh[lane * 8 + k];

    #pragma unroll 4
    for (int r = 0; r < RPW; ++r) {
        const size_t row_g = (size_t)m * NN + blk * BROWS + w * RPW + r;
        const float a = A[row_g];
        float e[8];
        load_row8<USE_E>(E32, S, row_g, lane, e);
        float* op = out + row_g * NN + lane * 8;
        reinterpret_cast<float4*>(op)[0] =
            make_float4(e[0]*a*b[0], e[1]*a*b[1], e[2]*a*b[2], e[3]*a*b[3]);
        reinterpret_cast<float4*>(op)[1] =
            make_float4(e[4]*a*b[4], e[5]*a*b[5], e[6]*a*b[6], e[7]*a*b[7]);
    }
}

extern "C" void kernel_launch(void* const* d_in, const int* in_sizes, int n_in,
                              void* d_out, int out_size, void* d_ws, size_t ws_size,
                              hipStream_t stream) {
    const float* S = reinterpret_cast<const float*>(d_in[0]);
    float* out = reinterpret_cast<float*>(d_out);
    const int nmat = in_sizes[0] / (NN * NN);   // 128 for (8,16,512,512)

    const size_t e_bytes   = (size_t)in_sizes[0] * 2;            // fp16 E
    const size_t pa_floats = (size_t)nmat * NBLK * NN;           // one partial buffer
    const size_t need      = e_bytes + (2 * pa_floats + (size_t)nmat * NN) * 4;

    dim3 g(nmat * NBLK), b(THREADS);
    if (d_ws != nullptr && ws_size >= need) {
        uint32_t* E32 = reinterpret_cast<uint32_t*>(d_ws);
        float* p0 = reinterpret_cast<float*>(reinterpret_cast<char*>(d_ws) + e_bytes);
        float* p1 = p0 + pa_floats;
        float* A  = p1 + pa_floats;
        k_first<true><<<g, b, 0, stream>>>(S, E32, A, p0, nmat);
        for (int t = 1; t < NITER; ++t)
            k_sweep<true><<<g, b, 0, stream>>>(E32, S, (t & 1) ? p0 : p1,
                                               (t & 1) ? p1 : p0, A, nmat);
        k_final<true><<<g, b, 0, stream>>>(E32, S, p1, A, out, nmat);   // t=9 wrote p1
    } else {
        // fallback: recompute exp(S) per sweep, only partials+A in ws
        float* p0 = reinterpret_cast<float*>(d_ws);
        float* p1 = p0 + pa_floats;
        float* A  = p1 + pa_floats;
        k_first<false><<<g, b, 0, stream>>>(S, nullptr, A, p0, nmat);
        for (int t = 1; t < NITER; ++t)
            k_sweep<false><<<g, b, 0, stream>>>(nullptr, S, (t & 1) ? p0 : p1,
                                                (t & 1) ? p1 : p0, A, nmat);
        k_final<false><<<g, b, 0, stream>>>(nullptr, S, p1, A, out, nmat);
    }
}

// Round 10
// 265.700 us; speedup vs baseline: 1.0928x; 1.0928x over previous
//
#include <hip/hip_runtime.h>
#include <hip/hip_fp16.h>

#define NN 512
#define NH 256             // half row
#define NBLK 4             // blocks per matrix
#define BROWS 128          // rows per block
#define THREADS 512        // 8 waves
#define NWAVE 8
#define RPW 16             // rows per wave
#define NITER 10

union H2U { uint32_t u; __half2 h; };

__device__ __forceinline__ float wave_reduce_sum(float v) {
    #pragma unroll
    for (int off = 32; off > 0; off >>= 1)
        v += __shfl_xor(v, off, 64);
    return v;   // all 64 lanes hold the sum
}

__device__ __forceinline__ uint4 pack8(const float e[8]) {
    H2U a, b, c, d;
    a.h = __floats2half2_rn(e[0], e[1]);
    b.h = __floats2half2_rn(e[2], e[3]);
    c.h = __floats2half2_rn(e[4], e[5]);
    d.h = __floats2half2_rn(e[6], e[7]);
    return make_uint4(a.u, b.u, c.u, d.u);
}

__device__ __forceinline__ void unpack8(uint4 q, float e[8]) {
    H2U u; float2 f;
    u.u = q.x; f = __half22float2(u.h); e[0] = f.x; e[1] = f.y;
    u.u = q.y; f = __half22float2(u.h); e[2] = f.x; e[3] = f.y;
    u.u = q.z; f = __half22float2(u.h); e[4] = f.x; e[5] = f.y;
    u.u = q.w; f = __half22float2(u.h); e[6] = f.x; e[7] = f.y;
}

// Lane->column map (coalescing fix, R9 lesson): slot k<4 -> col lane*4+k,
// slot k>=4 -> col 256+lane*4+(k-4). Every fp32 row access is then ONE
// contiguous float4 per half-row (64 lanes x 16B = 1KB/instruction), matching
// the fp16 sweep pattern that measured ~6 TB/s. The old lane*8 + p[0]/p[1]
// pattern made every fp32 instruction a 16B-at-32B-stride access (2x
// transactions) -> k_first/k_final ran at 2 TB/s.
// E is stored in slot order (uint4 of 8 fp16), so sweeps are unchanged.

template<bool USE_E>
__device__ __forceinline__ void load_row8(const uint32_t* __restrict__ E32,
                                          const float* __restrict__ S,
                                          size_t row_g, int lane, float e[8]) {
    if constexpr (USE_E) {
        uint4 q = *reinterpret_cast<const uint4*>(E32 + row_g * (NN / 2) + lane * 4);
        unpack8(q, e);
    } else {
        float4 q0 = *reinterpret_cast<const float4*>(S + row_g * NN + lane * 4);
        float4 q1 = *reinterpret_cast<const float4*>(S + row_g * NN + NH + lane * 4);
        e[0] = __expf(q0.x); e[1] = __expf(q0.y); e[2] = __expf(q0.z); e[3] = __expf(q0.w);
        e[4] = __expf(q1.x); e[5] = __expf(q1.y); e[6] = __expf(q1.z); e[7] = __expf(q1.w);
    }
}

template<bool USE_E>
__global__ __launch_bounds__(THREADS)
void k_first(const float* __restrict__ S, uint32_t* __restrict__ E32,
             float* __restrict__ A, float* __restrict__ pw, int nmat) {
    const int m = blockIdx.x % nmat, blk = blockIdx.x / nmat;
    const int lane = threadIdx.x & 63, w = threadIdx.x >> 6;
    __shared__ float part[NWAVE][NN];

    float c[8] = {0.f, 0.f, 0.f, 0.f, 0.f, 0.f, 0.f, 0.f};
    #pragma unroll 4
    for (int r = 0; r < RPW; ++r) {
        const size_t row_g = (size_t)m * NN + blk * BROWS + w * RPW + r;
        float4 q0 = *reinterpret_cast<const float4*>(S + row_g * NN + lane * 4);
        float4 q1 = *reinterpret_cast<const float4*>(S + row_g * NN + NH + lane * 4);
        float e[8];
        e[0] = __expf(q0.x); e[1] = __expf(q0.y); e[2] = __expf(q0.z); e[3] = __expf(q0.w);
        e[4] = __expf(q1.x); e[5] = __expf(q1.y); e[6] = __expf(q1.z); e[7] = __expf(q1.w);
        if constexpr (USE_E)
            *reinterpret_cast<uint4*>(E32 + row_g * (NN / 2) + lane * 4) = pack8(e);
        float rs = wave_reduce_sum(((e[0]+e[1])+(e[2]+e[3]))+((e[4]+e[5])+(e[6]+e[7])));
        const float a = 1.0f / rs;
        if (lane == 0) A[row_g] = a;
        #pragma unroll
        for (int k = 0; k < 8; ++k) c[k] += e[k] * a;
    }
    *reinterpret_cast<float4*>(&part[w][lane * 4])      = make_float4(c[0], c[1], c[2], c[3]);
    *reinterpret_cast<float4*>(&part[w][NH + lane * 4]) = make_float4(c[4], c[5], c[6], c[7]);
    __syncthreads();
    {
        const int j = threadIdx.x;   // 512 threads cover NN columns
        float s = 0.f;
        #pragma unroll
        for (int k = 0; k < NWAVE; ++k) s += part[k][j];
        pw[((size_t)m * NBLK + blk) * NN + j] = s;
    }
}

template<bool USE_E>
__global__ __launch_bounds__(THREADS)
void k_sweep(const uint32_t* __restrict__ E32, const float* __restrict__ S,
             const float* __restrict__ pr, float* __restrict__ pw,
             float* __restrict__ A, int nmat) {
    const int m = blockIdx.x % nmat, blk = blockIdx.x / nmat;
    const int lane = threadIdx.x & 63, w = threadIdx.x >> 6;
    __shared__ float Bsh[NN];
    __shared__ float part[NWAVE][NN];

    {   // B-phase: complete previous col sums (fixed order, deterministic)
        const int j = threadIdx.x;
        float s = 0.f;
        #pragma unroll
        for (int k = 0; k < NBLK; ++k) s += pr[((size_t)m * NBLK + k) * NN + j];
        Bsh[j] = 1.0f / s;
    }
    __syncthreads();

    float b[8];
    {
        float4 b0 = *reinterpret_cast<float4*>(&Bsh[lane * 4]);
        float4 b1 = *reinterpret_cast<float4*>(&Bsh[NH + lane * 4]);
        b[0] = b0.x; b[1] = b0.y; b[2] = b0.z; b[3] = b0.w;
        b[4] = b1.x; b[5] = b1.y; b[6] = b1.z; b[7] = b1.w;
    }
    float c[8] = {0.f, 0.f, 0.f, 0.f, 0.f, 0.f, 0.f, 0.f};

    #pragma unroll 4
    for (int r = 0; r < RPW; ++r) {
        const size_t row_g = (size_t)m * NN + blk * BROWS + w * RPW + r;
        float e[8];
        load_row8<USE_E>(E32, S, row_g, lane, e);
        float d = ((e[0]*b[0] + e[1]*b[1]) + (e[2]*b[2] + e[3]*b[3])) +
                  ((e[4]*b[4] + e[5]*b[5]) + (e[6]*b[6] + e[7]*b[7]));
        d = wave_reduce_sum(d);
        const float a = 1.0f / d;
        if (lane == 0) A[row_g] = a;
        #pragma unroll
        for (int k = 0; k < 8; ++k) c[k] += e[k] * a;
    }
    *reinterpret_cast<float4*>(&part[w][lane * 4])      = make_float4(c[0], c[1], c[2], c[3]);
    *reinterpret_cast<float4*>(&part[w][NH + lane * 4]) = make_float4(c[4], c[5], c[6], c[7]);
    __syncthreads();
    {
        const int j = threadIdx.x;
        float s = 0.f;
        #pragma unroll
        for (int k = 0; k < NWAVE; ++k) s += part[k][j];
        pw[((size_t)m * NBLK + blk) * NN + j] = s;
    }
}

template<bool USE_E>
__global__ __launch_bounds__(THREADS)
void k_final(const uint32_t* __restrict__ E32, const float* __restrict__ S,
             const float* __restrict__ pr, const float* __restrict__ A,
             float* __restrict__ out, int nmat) {
    const int m = blockIdx.x % nmat, blk = blockIdx.x / nmat;
    const int lane = threadIdx.x & 63, w = threadIdx.x >> 6;
    __shared__ float Bsh[NN];

    {
        const int j = threadIdx.x;
        float s = 0.f;
        #pragma unroll
        for (int k = 0; k < NBLK; ++k) s += pr[((size_t)m * NBLK + k) * NN + j];
        Bsh[j] = 1.0f / s;
    }
    __syncthreads();

    float b[8];
    {
        float4 b0 = *reinterpret_cast<float4*>(&Bsh[lane * 4]);
        float4 b1 = *reinterpret_cast<float4*>(&Bsh[NH + lane * 4]);
        b[0] = b0.x; b[1] = b0.y; b[2] = b0.z; b[3] = b0.w;
        b[4] = b1.x; b[5] = b1.y; b[6] = b1.z; b[7] = b1.w;
    }

    #pragma unroll 4
    for (int r = 0; r < RPW; ++r) {
        const size_t row_g = (size_t)m * NN + blk * BROWS + w * RPW + r;
        const float a = A[row_g];
        float e[8];
        load_row8<USE_E>(E32, S, row_g, lane, e);
        *reinterpret_cast<float4*>(out + row_g * NN + lane * 4) =
            make_float4(e[0]*a*b[0], e[1]*a*b[1], e[2]*a*b[2], e[3]*a*b[3]);
        *reinterpret_cast<float4*>(out + row_g * NN + NH + lane * 4) =
            make_float4(e[4]*a*b[4], e[5]*a*b[5], e[6]*a*b[6], e[7]*a*b[7]);
    }
}

extern "C" void kernel_launch(void* const* d_in, const int* in_sizes, int n_in,
                              void* d_out, int out_size, void* d_ws, size_t ws_size,
                              hipStream_t stream) {
    const float* S = reinterpret_cast<const float*>(d_in[0]);
    float* out = reinterpret_cast<float*>(d_out);
    const int nmat = in_sizes[0] / (NN * NN);   // 128 for (8,16,512,512)

    const size_t e_bytes   = (size_t)in_sizes[0] * 2;            // fp16 E
    const size_t pa_floats = (size_t)nmat * NBLK * NN;           // one partial buffer
    const size_t need      = e_bytes + (2 * pa_floats + (size_t)nmat * NN) * 4;

    dim3 g(nmat * NBLK), b(THREADS);
    if (d_ws != nullptr && ws_size >= need) {
        uint32_t* E32 = reinterpret_cast<uint32_t*>(d_ws);
        float* p0 = reinterpret_cast<float*>(reinterpret_cast<char*>(d_ws) + e_bytes);
        float* p1 = p0 + pa_floats;
        float* A  = p1 + pa_floats;
        k_first<true><<<g, b, 0, stream>>>(S, E32, A, p0, nmat);
        for (int t = 1; t < NITER; ++t)
            k_sweep<true><<<g, b, 0, stream>>>(E32, S, (t & 1) ? p0 : p1,
                                               (t & 1) ? p1 : p0, A, nmat);
        k_final<true><<<g, b, 0, stream>>>(E32, S, p1, A, out, nmat);   // t=9 wrote p1
    } else {
        // fallback: recompute exp(S) per sweep, only partials+A in ws
        float* p0 = reinterpret_cast<float*>(d_ws);
        float* p1 = p0 + pa_floats;
        float* A  = p1 + pa_floats;
        k_first<false><<<g, b, 0, stream>>>(S, nullptr, A, p0, nmat);
        for (int t = 1; t < NITER; ++t)
            k_sweep<false><<<g, b, 0, stream>>>(nullptr, S, (t & 1) ? p0 : p1,
                                                (t & 1) ? p1 : p0, A, nmat);
        k_final<false><<<g, b, 0, stream>>>(nullptr, S, p1, A, out, nmat);
    }
}

// Round 11
// 252.933 us; speedup vs baseline: 1.1479x; 1.0505x over previous
//
#include <hip/hip_runtime.h>
#include <hip/hip_fp16.h>

#define NN 512
#define NH 256             // half row
#define NBLK 4             // blocks per matrix (sweep/final)
#define BROWS 128          // rows per block
#define THREADS 512        // 8 waves
#define NWAVE 8
#define RPW 16             // rows per wave
#define NITER 10

union H2U { uint32_t u; __half2 h; };

__device__ __forceinline__ float wave_reduce_sum(float v) {
    #pragma unroll
    for (int off = 32; off > 0; off >>= 1)
        v += __shfl_xor(v, off, 64);
    return v;   // all 64 lanes hold the sum
}

__device__ __forceinline__ uint4 pack8(const float e[8]) {
    H2U a, b, c, d;
    a.h = __floats2half2_rn(e[0], e[1]);
    b.h = __floats2half2_rn(e[2], e[3]);
    c.h = __floats2half2_rn(e[4], e[5]);
    d.h = __floats2half2_rn(e[6], e[7]);
    return make_uint4(a.u, b.u, c.u, d.u);
}

__device__ __forceinline__ void unpack8(uint4 q, float e[8]) {
    H2U u; float2 f;
    u.u = q.x; f = __half22float2(u.h); e[0] = f.x; e[1] = f.y;
    u.u = q.y; f = __half22float2(u.h); e[2] = f.x; e[3] = f.y;
    u.u = q.z; f = __half22float2(u.h); e[4] = f.x; e[5] = f.y;
    u.u = q.w; f = __half22float2(u.h); e[6] = f.x; e[7] = f.y;
}

// Lane->column map: slot k<4 -> col lane*4+k, slot k>=4 -> col 256+lane*4+
// (k-4). Every access (fp32 and fp16) is one contiguous 16B per lane.

// R10 lesson: the fused exp+rowsum kernel sat at 90us across 3 geometries
// with NO pipe saturated (HBM 1.5/6.3 TB/s, VALU 7%) -- the per-row serial
// dependency chain (load->exp->6-deep shfl reduce->rcp) is the cost.
// Split: k_exp = pure grid-stride stream S->E (no cross-lane deps at all);
// the rowsum/partial work moves into an extra sweep with B=1 that reads E
// from L3 at sweep speed.

__global__ __launch_bounds__(256)
void k_exp(const float* __restrict__ S, uint32_t* __restrict__ E32,
           size_t nchunk) {
    size_t idx = (size_t)blockIdx.x * 256 + threadIdx.x;
    const size_t stride = (size_t)gridDim.x * 256;
    for (; idx < nchunk; idx += stride) {
        const size_t row = idx >> 6;      // 64 chunks per row
        const int    ln  = idx & 63;
        const float* rp = S + row * NN;
        float4 q0 = *reinterpret_cast<const float4*>(rp + ln * 4);
        float4 q1 = *reinterpret_cast<const float4*>(rp + NH + ln * 4);
        float e[8];
        e[0] = __expf(q0.x); e[1] = __expf(q0.y); e[2] = __expf(q0.z); e[3] = __expf(q0.w);
        e[4] = __expf(q1.x); e[5] = __expf(q1.y); e[6] = __expf(q1.z); e[7] = __expf(q1.w);
        *reinterpret_cast<uint4*>(E32 + idx * 4) = pack8(e);
    }
}

template<bool USE_E>
__device__ __forceinline__ void load_row8(const uint32_t* __restrict__ E32,
                                          const float* __restrict__ S,
                                          size_t row_g, int lane, float e[8]) {
    if constexpr (USE_E) {
        uint4 q = *reinterpret_cast<const uint4*>(E32 + row_g * (NN / 2) + lane * 4);
        unpack8(q, e);
    } else {
        float4 q0 = *reinterpret_cast<const float4*>(S + row_g * NN + lane * 4);
        float4 q1 = *reinterpret_cast<const float4*>(S + row_g * NN + NH + lane * 4);
        e[0] = __expf(q0.x); e[1] = __expf(q0.y); e[2] = __expf(q0.z); e[3] = __expf(q0.w);
        e[4] = __expf(q1.x); e[5] = __expf(q1.y); e[6] = __expf(q1.z); e[7] = __expf(q1.w);
    }
}

// One Sinkhorn iteration: A_i = 1/dot(E_i, B_prev) (B_prev=1 when FIRST),
// col partials c_j += E_ij*A_i -> per-block partial vector (parity dbuf).
template<bool USE_E, bool FIRST>
__global__ __launch_bounds__(THREADS)
void k_sweep(const uint32_t* __restrict__ E32, const float* __restrict__ S,
             const float* __restrict__ pr, float* __restrict__ pw,
             float* __restrict__ A, int nmat) {
    const int m = blockIdx.x % nmat, blk = blockIdx.x / nmat;
    const int lane = threadIdx.x & 63, w = threadIdx.x >> 6;
    __shared__ float Bsh[NN];
    __shared__ float part[NWAVE][NN];

    if constexpr (!FIRST) {   // complete previous col sums (fixed order)
        const int j = threadIdx.x;
        float s = 0.f;
        #pragma unroll
        for (int k = 0; k < NBLK; ++k) s += pr[((size_t)m * NBLK + k) * NN + j];
        Bsh[j] = 1.0f / s;
        __syncthreads();
    }

    float b[8];
    if constexpr (FIRST) {
        #pragma unroll
        for (int k = 0; k < 8; ++k) b[k] = 1.0f;
    } else {
        float4 b0 = *reinterpret_cast<float4*>(&Bsh[lane * 4]);
        float4 b1 = *reinterpret_cast<float4*>(&Bsh[NH + lane * 4]);
        b[0] = b0.x; b[1] = b0.y; b[2] = b0.z; b[3] = b0.w;
        b[4] = b1.x; b[5] = b1.y; b[6] = b1.z; b[7] = b1.w;
    }
    float c[8] = {0.f, 0.f, 0.f, 0.f, 0.f, 0.f, 0.f, 0.f};

    #pragma unroll 4
    for (int r = 0; r < RPW; ++r) {
        const size_t row_g = (size_t)m * NN + blk * BROWS + w * RPW + r;
        float e[8];
        load_row8<USE_E>(E32, S, row_g, lane, e);
        float d = ((e[0]*b[0] + e[1]*b[1]) + (e[2]*b[2] + e[3]*b[3])) +
                  ((e[4]*b[4] + e[5]*b[5]) + (e[6]*b[6] + e[7]*b[7]));
        d = wave_reduce_sum(d);
        const float a = 1.0f / d;
        if (lane == 0) A[row_g] = a;
        #pragma unroll
        for (int k = 0; k < 8; ++k) c[k] += e[k] * a;
    }
    *reinterpret_cast<float4*>(&part[w][lane * 4])      = make_float4(c[0], c[1], c[2], c[3]);
    *reinterpret_cast<float4*>(&part[w][NH + lane * 4]) = make_float4(c[4], c[5], c[6], c[7]);
    __syncthreads();
    {
        const int j = threadIdx.x;
        float s = 0.f;
        #pragma unroll
        for (int k = 0; k < NWAVE; ++k) s += part[k][j];
        pw[((size_t)m * NBLK + blk) * NN + j] = s;
    }
}

template<bool USE_E>
__global__ __launch_bounds__(THREADS)
void k_final(const uint32_t* __restrict__ E32, const float* __restrict__ S,
             const float* __restrict__ pr, const float* __restrict__ A,
             float* __restrict__ out, int nmat) {
    const int m = blockIdx.x % nmat, blk = blockIdx.x / nmat;
    const int lane = threadIdx.x & 63, w = threadIdx.x >> 6;
    __shared__ float Bsh[NN];

    {
        const int j = threadIdx.x;
        float s = 0.f;
        #pragma unroll
        for (int k = 0; k < NBLK; ++k) s += pr[((size_t)m * NBLK + k) * NN + j];
        Bsh[j] = 1.0f / s;
    }
    __syncthreads();

    float b[8];
    {
        float4 b0 = *reinterpret_cast<float4*>(&Bsh[lane * 4]);
        float4 b1 = *reinterpret_cast<float4*>(&Bsh[NH + lane * 4]);
        b[0] = b0.x; b[1] = b0.y; b[2] = b0.z; b[3] = b0.w;
        b[4] = b1.x; b[5] = b1.y; b[6] = b1.z; b[7] = b1.w;
    }

    #pragma unroll 4
    for (int r = 0; r < RPW; ++r) {
        const size_t row_g = (size_t)m * NN + blk * BROWS + w * RPW + r;
        const float a = A[row_g];
        float e[8];
        load_row8<USE_E>(E32, S, row_g, lane, e);
        *reinterpret_cast<float4*>(out + row_g * NN + lane * 4) =
            make_float4(e[0]*a*b[0], e[1]*a*b[1], e[2]*a*b[2], e[3]*a*b[3]);
        *reinterpret_cast<float4*>(out + row_g * NN + NH + lane * 4) =
            make_float4(e[4]*a*b[4], e[5]*a*b[5], e[6]*a*b[6], e[7]*a*b[7]);
    }
}

extern "C" void kernel_launch(void* const* d_in, const int* in_sizes, int n_in,
                              void* d_out, int out_size, void* d_ws, size_t ws_size,
                              hipStream_t stream) {
    const float* S = reinterpret_cast<const float*>(d_in[0]);
    float* out = reinterpret_cast<float*>(d_out);
    const int nmat = in_sizes[0] / (NN * NN);   // 128 for (8,16,512,512)

    const size_t e_bytes   = (size_t)in_sizes[0] * 2;            // fp16 E
    const size_t pa_floats = (size_t)nmat * NBLK * NN;           // one partial buffer
    const size_t need      = e_bytes + (2 * pa_floats + (size_t)nmat * NN) * 4;

    dim3 g(nmat * NBLK), b(THREADS);
    if (d_ws != nullptr && ws_size >= need) {
        uint32_t* E32 = reinterpret_cast<uint32_t*>(d_ws);
        float* p0 = reinterpret_cast<float*>(reinterpret_cast<char*>(d_ws) + e_bytes);
        float* p1 = p0 + pa_floats;
        float* A  = p1 + pa_floats;

        const size_t nchunk = (size_t)in_sizes[0] / 8;
        k_exp<<<dim3(2048), dim3(256), 0, stream>>>(S, E32, nchunk);

        // sweeps t=0..9: t reads p[(t+1)&1], writes p[t&1]; t=0 uses B=1
        k_sweep<true, true><<<g, b, 0, stream>>>(E32, S, nullptr, p0, A, nmat);
        for (int t = 1; t < NITER; ++t)
            k_sweep<true, false><<<g, b, 0, stream>>>(E32, S, (t & 1) ? p0 : p1,
                                                      (t & 1) ? p1 : p0, A, nmat);
        k_final<true><<<g, b, 0, stream>>>(E32, S, p1, A, out, nmat);   // t=9 wrote p1
    } else {
        // fallback: recompute exp(S) per sweep, only partials+A in ws
        float* p0 = reinterpret_cast<float*>(d_ws);
        float* p1 = p0 + pa_floats;
        float* A  = p1 + pa_floats;
        k_sweep<false, true><<<g, b, 0, stream>>>(nullptr, S, nullptr, p0, A, nmat);
        for (int t = 1; t < NITER; ++t)
            k_sweep<false, false><<<g, b, 0, stream>>>(nullptr, S, (t & 1) ? p0 : p1,
                                                       (t & 1) ? p1 : p0, A, nmat);
        k_final<false><<<g, b, 0, stream>>>(nullptr, S, p1, A, out, nmat);
    }
}